// Round 5
// baseline (550.229 us; speedup 1.0000x reference)
//
#include <hip/hip_runtime.h>
#include <hip/hip_bf16.h>
#include <math.h>

#define NEGV -9e15f

typedef short bf16x8 __attribute__((ext_vector_type(8)));
typedef float f32x4 __attribute__((ext_vector_type(4)));

__device__ __forceinline__ unsigned short f2bf(float x) {
  unsigned u = __float_as_uint(x);
  u += 0x7fffu + ((u >> 16) & 1u);
  return (unsigned short)(u >> 16);
}

__device__ __forceinline__ unsigned pk2(float a, float b) {
  __hip_bfloat162 h = __float22bfloat162_rn(make_float2(a, b));
  unsigned u;
  __builtin_memcpy(&u, &h, 4);
  return u;
}

// branchless mish: x * n/(n+2), n = u(u+2), u = e^min(x,30)
__device__ __forceinline__ float mishf(float x) {
  float u = __expf(fminf(x, 30.0f));
  float n = u * (u + 2.0f);
  return x * __fdividef(n, n + 2.0f);
}

// ---------------- s[k] = sum_vd v[k][vd] ----------------
__global__ void svec_kernel(const float* __restrict__ v, float* __restrict__ s) {
  int r = blockIdx.x;
  int lane = threadIdx.x;  // 64
  float4 a = *reinterpret_cast<const float4*>(v + (size_t)r * 256 + lane * 4);
  float x = a.x + a.y + a.z + a.w;
  for (int off = 32; off; off >>= 1) x += __shfl_down(x, off);
  if (lane == 0) s[r] = x;
}

// ---------------- C[1024x256] = A[1024x256] @ W[256x256] + bvec ----------------
__global__ __launch_bounds__(256) void gemm1024(
    const float* __restrict__ A, const float* __restrict__ W,
    const float* __restrict__ bvec, float* __restrict__ C, int perm) {
  __shared__ float sAT[16][68];
  __shared__ float sW[16][68];
  int tid = threadIdx.x;
  int c0 = blockIdx.x * 64, r0 = blockIdx.y * 64;
  int ty = tid >> 4, tx = tid & 15;
  float acc[4][4] = {};
  for (int k0 = 0; k0 < 256; k0 += 16) {
    {
      int r = tid >> 2, jq = tid & 3;
      float4 a4 = *reinterpret_cast<const float4*>(A + (size_t)(r0 + r) * 256 + k0 + jq * 4);
      sAT[jq * 4 + 0][r] = a4.x;
      sAT[jq * 4 + 1][r] = a4.y;
      sAT[jq * 4 + 2][r] = a4.z;
      sAT[jq * 4 + 3][r] = a4.w;
    }
    {
      int kk = tid >> 4, cq = tid & 15;
      int gk = k0 + kk;
      int row = perm ? ((gk & 63) * 4 + (gk >> 6)) : gk;
      float4 w4 = *reinterpret_cast<const float4*>(W + (size_t)row * 256 + c0 + cq * 4);
      *reinterpret_cast<float4*>(&sW[kk][cq * 4]) = w4;
    }
    __syncthreads();
#pragma unroll
    for (int kk = 0; kk < 16; ++kk) {
      float4 av = *reinterpret_cast<const float4*>(&sAT[kk][ty * 4]);
      float4 bv = *reinterpret_cast<const float4*>(&sW[kk][tx * 4]);
      float a[4] = {av.x, av.y, av.z, av.w};
      float b[4] = {bv.x, bv.y, bv.z, bv.w};
#pragma unroll
      for (int i = 0; i < 4; ++i)
#pragma unroll
        for (int j = 0; j < 4; ++j) acc[i][j] = fmaf(a[i], b[j], acc[i][j]);
    }
    __syncthreads();
  }
#pragma unroll
  for (int i = 0; i < 4; ++i) {
    int rr = r0 + ty * 4 + i, cc = c0 + tx * 4;
    float4 o;
    o.x = acc[i][0] + bvec[cc + 0];
    o.y = acc[i][1] + bvec[cc + 1];
    o.z = acc[i][2] + bvec[cc + 2];
    o.w = acc[i][3] + bvec[cc + 3];
    *reinterpret_cast<float4*>(C + (size_t)rr * 256 + cc) = o;
  }
}

// ---------------- out = LN(x0 + mish(y)) * g + be ----------------
__global__ __launch_bounds__(256) void ln_epilogue(
    const float* __restrict__ x0, const float* __restrict__ y,
    const float* __restrict__ g, const float* __restrict__ be,
    float* __restrict__ out) {
  __shared__ float r1[5], r2[5];
  int r = blockIdx.x, t = threadIdx.x;
  int wid = t >> 6, lane = t & 63;
  float x = x0[(size_t)r * 256 + t] + mishf(y[(size_t)r * 256 + t]);
  float a = x, b = x * x;
  for (int off = 32; off; off >>= 1) {
    a += __shfl_down(a, off);
    b += __shfl_down(b, off);
  }
  if (lane == 0) { r1[wid] = a; r2[wid] = b; }
  __syncthreads();
  if (t == 0) {
    r1[4] = r1[0] + r1[1] + r1[2] + r1[3];
    r2[4] = r2[0] + r2[1] + r2[2] + r2[3];
  }
  __syncthreads();
  float m = r1[4] * (1.0f / 256.0f);
  float var = r2[4] * (1.0f / 256.0f) - m * m;
  out[(size_t)r * 256 + t] = (x - m) * rsqrtf(var + 1e-5f) * g[t] + be[t];
}

// ---------------- fused bias path, MFMA bf16, single P buffer, full residency ----------------
#define PSTR 168  // bf16 elems per P row (160 + 8 pad) -> 336 B stride, 16B-aligned
#define BTILES 16

__device__ __forceinline__ void pack_store(unsigned short* p, f32x4 v) {
  uint2 w;
  w.x = pk2(v[0], v[1]);
  w.y = pk2(v[2], v[3]);
  *reinterpret_cast<uint2*>(p) = w;
}

// GEMM2 for tile with rows PO..PO+15 from per-wave P buffer SPR; Wo frags in regs
#define G2_STEP(SPR, PO) do {                                                          \
    bf16x8 pf0 = *reinterpret_cast<const bf16x8*>((SPR) + r * PSTR + 0 + g * 8);       \
    bf16x8 pf1 = *reinterpret_cast<const bf16x8*>((SPR) + r * PSTR + 32 + g * 8);      \
    bf16x8 pf2 = *reinterpret_cast<const bf16x8*>((SPR) + r * PSTR + 64 + g * 8);      \
    bf16x8 pf3 = *reinterpret_cast<const bf16x8*>((SPR) + r * PSTR + 96 + g * 8);      \
    bf16x8 pf4 = *reinterpret_cast<const bf16x8*>((SPR) + r * PSTR + 128 + g * 8);     \
    f32x4 o0 = {boreg0, boreg0, boreg0, boreg0};                                       \
    f32x4 o1 = {boreg1, boreg1, boreg1, boreg1};                                       \
    f32x4 o2 = {boreg2, boreg2, boreg2, boreg2};                                       \
    o0 = __builtin_amdgcn_mfma_f32_16x16x32_bf16(pf0, wof[0][0], o0, 0, 0, 0);         \
    o1 = __builtin_amdgcn_mfma_f32_16x16x32_bf16(pf0, wof[1][0], o1, 0, 0, 0);         \
    o2 = __builtin_amdgcn_mfma_f32_16x16x32_bf16(pf0, wof[2][0], o2, 0, 0, 0);         \
    o0 = __builtin_amdgcn_mfma_f32_16x16x32_bf16(pf1, wof[0][1], o0, 0, 0, 0);         \
    o1 = __builtin_amdgcn_mfma_f32_16x16x32_bf16(pf1, wof[1][1], o1, 0, 0, 0);         \
    o2 = __builtin_amdgcn_mfma_f32_16x16x32_bf16(pf1, wof[2][1], o2, 0, 0, 0);         \
    o0 = __builtin_amdgcn_mfma_f32_16x16x32_bf16(pf2, wof[0][2], o0, 0, 0, 0);         \
    o1 = __builtin_amdgcn_mfma_f32_16x16x32_bf16(pf2, wof[1][2], o1, 0, 0, 0);         \
    o2 = __builtin_amdgcn_mfma_f32_16x16x32_bf16(pf2, wof[2][2], o2, 0, 0, 0);         \
    o0 = __builtin_amdgcn_mfma_f32_16x16x32_bf16(pf3, wof[0][3], o0, 0, 0, 0);         \
    o1 = __builtin_amdgcn_mfma_f32_16x16x32_bf16(pf3, wof[1][3], o1, 0, 0, 0);         \
    o2 = __builtin_amdgcn_mfma_f32_16x16x32_bf16(pf3, wof[2][3], o2, 0, 0, 0);         \
    o0 = __builtin_amdgcn_mfma_f32_16x16x32_bf16(pf4, wof[0][4], o0, 0, 0, 0);         \
    o1 = __builtin_amdgcn_mfma_f32_16x16x32_bf16(pf4, wof[1][4], o1, 0, 0, 0);         \
    o2 = __builtin_amdgcn_mfma_f32_16x16x32_bf16(pf4, wof[2][4], o2, 0, 0, 0);         \
    float* bp = bout + (size_t)((PO) + g * 4) * 40;                                    \
    _Pragma("unroll")                                                                  \
    for (int reg = 0; reg < 4; ++reg) {                                                \
      bp[reg * 40 + r] = mishf(o0[reg]);                                               \
      bp[reg * 40 + 16 + r] = mishf(o1[reg]);                                          \
      if (r < 8) bp[reg * 40 + 32 + r] = mishf(o2[reg]);                               \
    }                                                                                  \
  } while (0)

// Per tile: build xf, prefetch t+1, G2(t-1) reads sP, G1(t) MFMAs+pack-writes sP, norms.
// Single buffer is safe: all G2 ds_reads precede G1 ds_writes; the 20 G1 MFMAs cover
// the WAR waitcnt.
#define TILE_STEP(SP, T, DOG2, DOPREF) do {                                            \
    const size_t p0 = row0 + (size_t)(T) * 16;                                         \
    bf16x8 xf0, xf1;                                                                   \
    {                                                                                  \
      uint4 t0 = {pk2(xA.x, xA.y), pk2(xA.z, xA.w), pk2(xB.x, xB.y), pk2(xB.z, xB.w)}; \
      unsigned d0 = (g == 1) ? 0x00003f80u : pk2(xC.x, xC.y);                          \
      uint4 t1 = {d0, pk2(xC.z, xC.w), pk2(xD.x, xD.y), pk2(xD.z, xD.w)};              \
      __builtin_memcpy(&xf0, &t0, 16);                                                 \
      __builtin_memcpy(&xf1, &t1, 16);                                                 \
    }                                                                                  \
    if (DOPREF) {                                                                      \
      const float* xr2 = bias + (p0 + 16 + r) * 40;                                    \
      xA = *reinterpret_cast<const float4*>(xr2 + g * 8);                              \
      xB = *reinterpret_cast<const float4*>(xr2 + g * 8 + 4);                          \
      xC = *reinterpret_cast<const float4*>(xr2 + 32);                                 \
      xD = *reinterpret_cast<const float4*>(xr2 + 36);                                 \
    }                                                                                  \
    if (DOG2) { G2_STEP(SP, p0 - 16); }                                                \
    float hv0, hv1, hv2, hv3;                                                          \
    {                                                                                  \
      f32x4 z = {0.0f, 0.0f, 0.0f, 0.0f};                                              \
      f32x4 q0 = z, q1 = z, q2 = z, q3 = z, q4 = z;                                    \
      q0 = __builtin_amdgcn_mfma_f32_16x16x32_bf16(wf[0][0], xf0, q0, 0, 0, 0);        \
      q1 = __builtin_amdgcn_mfma_f32_16x16x32_bf16(wf[1][0], xf0, q1, 0, 0, 0);        \
      q2 = __builtin_amdgcn_mfma_f32_16x16x32_bf16(wf[2][0], xf0, q2, 0, 0, 0);        \
      q3 = __builtin_amdgcn_mfma_f32_16x16x32_bf16(wf[3][0], xf0, q3, 0, 0, 0);        \
      q4 = __builtin_amdgcn_mfma_f32_16x16x32_bf16(wf[4][0], xf0, q4, 0, 0, 0);        \
      q0 = __builtin_amdgcn_mfma_f32_16x16x32_bf16(wf[0][1], xf1, q0, 0, 0, 0);        \
      q1 = __builtin_amdgcn_mfma_f32_16x16x32_bf16(wf[1][1], xf1, q1, 0, 0, 0);        \
      q2 = __builtin_amdgcn_mfma_f32_16x16x32_bf16(wf[2][1], xf1, q2, 0, 0, 0);        \
      q3 = __builtin_amdgcn_mfma_f32_16x16x32_bf16(wf[3][1], xf1, q3, 0, 0, 0);        \
      q4 = __builtin_amdgcn_mfma_f32_16x16x32_bf16(wf[4][1], xf1, q4, 0, 0, 0);        \
      float cs0 = q0[0]*q0[0] + q0[1]*q0[1] + q0[2]*q0[2] + q0[3]*q0[3];               \
      float cs1 = q1[0]*q1[0] + q1[1]*q1[1] + q1[2]*q1[2] + q1[3]*q1[3];               \
      float cs2 = q2[0]*q2[0] + q2[1]*q2[1] + q2[2]*q2[2] + q2[3]*q2[3];               \
      float cs3 = q3[0]*q3[0] + q3[1]*q3[1] + q3[2]*q3[2] + q3[3]*q3[3];               \
      float cs4 = q4[0]*q4[0] + q4[1]*q4[1] + q4[2]*q4[2] + q4[3]*q4[3];               \
      pack_store((SP) + r * PSTR + 0 * 16 + g * 4, q0);                                \
      pack_store((SP) + r * PSTR + 1 * 16 + g * 4, q1);                                \
      pack_store((SP) + r * PSTR + 2 * 16 + g * 4, q2);                                \
      pack_store((SP) + r * PSTR + 3 * 16 + g * 4, q3);                                \
      pack_store((SP) + r * PSTR + 4 * 16 + g * 4, q4);                                \
      hv0 = cs0 + cs1 + ((g < 2) ? cs2 : 0.0f);                                        \
      hv1 = ((g < 2) ? 0.0f : cs2) + cs3 + cs4;                                        \
    }                                                                                  \
    {                                                                                  \
      f32x4 z = {0.0f, 0.0f, 0.0f, 0.0f};                                              \
      f32x4 q0 = z, q1 = z, q2 = z, q3 = z, q4 = z;                                    \
      q0 = __builtin_amdgcn_mfma_f32_16x16x32_bf16(wf[5][0], xf0, q0, 0, 0, 0);        \
      q1 = __builtin_amdgcn_mfma_f32_16x16x32_bf16(wf[6][0], xf0, q1, 0, 0, 0);        \
      q2 = __builtin_amdgcn_mfma_f32_16x16x32_bf16(wf[7][0], xf0, q2, 0, 0, 0);        \
      q3 = __builtin_amdgcn_mfma_f32_16x16x32_bf16(wf[8][0], xf0, q3, 0, 0, 0);        \
      q4 = __builtin_amdgcn_mfma_f32_16x16x32_bf16(wf[9][0], xf0, q4, 0, 0, 0);        \
      q0 = __builtin_amdgcn_mfma_f32_16x16x32_bf16(wf[5][1], xf1, q0, 0, 0, 0);        \
      q1 = __builtin_amdgcn_mfma_f32_16x16x32_bf16(wf[6][1], xf1, q1, 0, 0, 0);        \
      q2 = __builtin_amdgcn_mfma_f32_16x16x32_bf16(wf[7][1], xf1, q2, 0, 0, 0);        \
      q3 = __builtin_amdgcn_mfma_f32_16x16x32_bf16(wf[8][1], xf1, q3, 0, 0, 0);        \
      q4 = __builtin_amdgcn_mfma_f32_16x16x32_bf16(wf[9][1], xf1, q4, 0, 0, 0);        \
      float cs5 = q0[0]*q0[0] + q0[1]*q0[1] + q0[2]*q0[2] + q0[3]*q0[3];               \
      float cs6 = q1[0]*q1[0] + q1[1]*q1[1] + q1[2]*q1[2] + q1[3]*q1[3];               \
      float cs7 = q2[0]*q2[0] + q2[1]*q2[1] + q2[2]*q2[2] + q2[3]*q2[3];               \
      float cs8 = q3[0]*q3[0] + q3[1]*q3[1] + q3[2]*q3[2] + q3[3]*q3[3];               \
      float cs9 = q4[0]*q4[0] + q4[1]*q4[1] + q4[2]*q4[2] + q4[3]*q4[3];               \
      pack_store((SP) + r * PSTR + 5 * 16 + g * 4, q0);                                \
      pack_store((SP) + r * PSTR + 6 * 16 + g * 4, q1);                                \
      pack_store((SP) + r * PSTR + 7 * 16 + g * 4, q2);                                \
      pack_store((SP) + r * PSTR + 8 * 16 + g * 4, q3);                                \
      pack_store((SP) + r * PSTR + 9 * 16 + g * 4, q4);                                \
      hv2 = cs5 + cs6 + ((g < 2) ? cs7 : 0.0f);                                        \
      hv3 = ((g < 2) ? 0.0f : cs7) + cs8 + cs9;                                        \
    }                                                                                  \
    hv0 += __shfl_xor(hv0, 16); hv0 += __shfl_xor(hv0, 32);                            \
    hv1 += __shfl_xor(hv1, 16); hv1 += __shfl_xor(hv1, 32);                            \
    hv2 += __shfl_xor(hv2, 16); hv2 += __shfl_xor(hv2, 32);                            \
    hv3 += __shfl_xor(hv3, 16); hv3 += __shfl_xor(hv3, 32);                            \
    float ss = (g == 0) ? hv0 : (g == 1) ? hv1 : (g == 2) ? hv2 : hv3;                 \
    diffs[(size_t)g * (1024 * 1024) + p0 + r] = sqrtf(ss);                             \
  } while (0)

__global__ __launch_bounds__(256, 4) void bias_mfma(
    const float* __restrict__ bias, const float* __restrict__ Wb,
    const float* __restrict__ bb, const float* __restrict__ Wo,
    const float* __restrict__ bo, float* __restrict__ diffs,
    float* __restrict__ bout) {
  __shared__ unsigned short sP[4][16 * PSTR];  // per-wave P buffer (single)
  int tid = threadIdx.x;
  int wv = tid >> 6, lane = tid & 63;
  int r = lane & 15, g = lane >> 4;

  // Wb^T fragments (A-operand): wf[n0][ks]; k=40 slot carries bb (bias fold)
  bf16x8 wf[10][2];
#pragma unroll
  for (int n0 = 0; n0 < 10; ++n0)
#pragma unroll
    for (int ks = 0; ks < 2; ++ks)
#pragma unroll
      for (int jj = 0; jj < 8; ++jj) {
        int k = ks * 32 + g * 8 + jj;
        int c = n0 * 16 + r;
        float w = (k < 40) ? Wb[k * 160 + c] : ((k == 40) ? bb[c] : 0.0f);
        wf[n0][ks][jj] = (short)f2bf(w);
      }
  // Wo^T fragments (B-operand for GEMM2): wof[n][ks]
  bf16x8 wof[3][5];
#pragma unroll
  for (int n = 0; n < 3; ++n)
#pragma unroll
    for (int ks = 0; ks < 5; ++ks)
#pragma unroll
      for (int jj = 0; jj < 8; ++jj) {
        int k = ks * 32 + g * 8 + jj;
        int c = n * 16 + r;
        wof[n][ks][jj] = (c < 40) ? (short)f2bf(Wo[k * 40 + c]) : (short)0;
      }
  float boreg0 = bo[r];
  float boreg1 = bo[16 + r];
  float boreg2 = (r < 8) ? bo[32 + r] : 0.0f;

  unsigned short* pP = &sP[wv][0];
  size_t row0 = ((size_t)blockIdx.x * 4 + wv) * (BTILES * 16);

  // prefetch tile 0
  const float* xr = bias + (row0 + r) * 40;
  float4 xA = *reinterpret_cast<const float4*>(xr + g * 8);
  float4 xB = *reinterpret_cast<const float4*>(xr + g * 8 + 4);
  float4 xC = *reinterpret_cast<const float4*>(xr + 32);
  float4 xD = *reinterpret_cast<const float4*>(xr + 36);

  TILE_STEP(pP, 0, false, true);
#pragma unroll 1
  for (int tt = 1; tt < BTILES - 1; ++tt) {
    TILE_STEP(pP, tt, true, true);
  }
  TILE_STEP(pP, BTILES - 1, true, false);
  G2_STEP(pP, row0 + (size_t)(BTILES - 1) * 16);
}

// ---------------- logits[h][q][k] = qk/8 + diffs, masked (in-place over diffs) ----------------
__global__ __launch_bounds__(256) void scores_kernel(
    const float* __restrict__ pq, const float* __restrict__ pk,
    const int* __restrict__ mask, float* __restrict__ logits) {
  __shared__ float sQT[64][68];
  __shared__ float sKT[64][68];
  int tid = threadIdx.x;
  int k0 = blockIdx.x * 64, q0 = blockIdx.y * 64, h = blockIdx.z;
  for (int i = tid; i < 1024; i += 256) {
    int r = i >> 4, dq = i & 15;
    float4 a = *reinterpret_cast<const float4*>(pq + (size_t)(q0 + r) * 256 + h * 64 + dq * 4);
    sQT[dq * 4 + 0][r] = a.x;
    sQT[dq * 4 + 1][r] = a.y;
    sQT[dq * 4 + 2][r] = a.z;
    sQT[dq * 4 + 3][r] = a.w;
    float4 b = *reinterpret_cast<const float4*>(pk + (size_t)(k0 + r) * 256 + h * 64 + dq * 4);
    sKT[dq * 4 + 0][r] = b.x;
    sKT[dq * 4 + 1][r] = b.y;
    sKT[dq * 4 + 2][r] = b.z;
    sKT[dq * 4 + 3][r] = b.w;
  }
  __syncthreads();
  int ty = tid >> 4, tx = tid & 15;
  float acc[4][4] = {};
#pragma unroll 4
  for (int d = 0; d < 64; ++d) {
    float4 av = *reinterpret_cast<const float4*>(&sQT[d][ty * 4]);
    float4 bv = *reinterpret_cast<const float4*>(&sKT[d][tx * 4]);
    float a[4] = {av.x, av.y, av.z, av.w};
    float b[4] = {bv.x, bv.y, bv.z, bv.w};
#pragma unroll
    for (int i = 0; i < 4; ++i)
#pragma unroll
      for (int j = 0; j < 4; ++j) acc[i][j] = fmaf(a[i], b[j], acc[i][j]);
  }
#pragma unroll
  for (int i = 0; i < 4; ++i) {
    int qq = q0 + ty * 4 + i;
    size_t base = (size_t)h * 1048576 + (size_t)qq * 1024 + k0 + tx * 4;
    float4 dv = *reinterpret_cast<const float4*>(logits + base);
    int4 mv = *reinterpret_cast<const int4*>(mask + (size_t)qq * 1024 + k0 + tx * 4);
    float4 o;
    o.x = (mv.x == 0) ? NEGV : fmaf(acc[i][0], 0.125f, dv.x);
    o.y = (mv.y == 0) ? NEGV : fmaf(acc[i][1], 0.125f, dv.y);
    o.z = (mv.z == 0) ? NEGV : fmaf(acc[i][2], 0.125f, dv.z);
    o.w = (mv.w == 0) ? NEGV : fmaf(acc[i][3], 0.125f, dv.w);
    *reinterpret_cast<float4*>(logits + base) = o;
  }
}

// ---------------- wave per (q, head): softmax over k, dot with s ----------------
__global__ __launch_bounds__(256) void softmax_dot(
    const float* __restrict__ logits, const float* __restrict__ sv,
    float* __restrict__ vm) {
  __shared__ float part[4];
  int q = blockIdx.x;
  int h = threadIdx.x >> 6, lane = threadIdx.x & 63;
  const float* lp = logits + (size_t)h * 1048576 + (size_t)q * 1024;
  float4 lv0 = *reinterpret_cast<const float4*>(lp + lane * 4);
  float4 lv1 = *reinterpret_cast<const float4*>(lp + 256 + lane * 4);
  float4 lv2 = *reinterpret_cast<const float4*>(lp + 512 + lane * 4);
  float4 lv3 = *reinterpret_cast<const float4*>(lp + 768 + lane * 4);
  float4 s0 = *reinterpret_cast<const float4*>(sv + lane * 4);
  float4 s1 = *reinterpret_cast<const float4*>(sv + 256 + lane * 4);
  float4 s2 = *reinterpret_cast<const float4*>(sv + 512 + lane * 4);
  float4 s3 = *reinterpret_cast<const float4*>(sv + 768 + lane * 4);
  float m = fmaxf(fmaxf(fmaxf(lv0.x, lv0.y), fmaxf(lv0.z, lv0.w)),
                  fmaxf(fmaxf(lv1.x, lv1.y), fmaxf(lv1.z, lv1.w)));
  m = fmaxf(m, fmaxf(fmaxf(fmaxf(lv2.x, lv2.y), fmaxf(lv2.z, lv2.w)),
                     fmaxf(fmaxf(lv3.x, lv3.y), fmaxf(lv3.z, lv3.w))));
#pragma unroll
  for (int off = 32; off; off >>= 1) m = fmaxf(m, __shfl_xor(m, off));
  float ps = 0.0f, pd = 0.0f;
  {
    float e;
    e = __expf(lv0.x - m); ps += e; pd = fmaf(e, s0.x, pd);
    e = __expf(lv0.y - m); ps += e; pd = fmaf(e, s0.y, pd);
    e = __expf(lv0.z - m); ps += e; pd = fmaf(e, s0.z, pd);
    e = __expf(lv0.w - m); ps += e; pd = fmaf(e, s0.w, pd);
    e = __expf(lv1.x - m); ps += e; pd = fmaf(e, s1.x, pd);
    e = __expf(lv1.y - m); ps += e; pd = fmaf(e, s1.y, pd);
    e = __expf(lv1.z - m); ps += e; pd = fmaf(e, s1.z, pd);
    e = __expf(lv1.w - m); ps += e; pd = fmaf(e, s1.w, pd);
    e = __expf(lv2.x - m); ps += e; pd = fmaf(e, s2.x, pd);
    e = __expf(lv2.y - m); ps += e; pd = fmaf(e, s2.y, pd);
    e = __expf(lv2.z - m); ps += e; pd = fmaf(e, s2.z, pd);
    e = __expf(lv2.w - m); ps += e; pd = fmaf(e, s2.w, pd);
    e = __expf(lv3.x - m); ps += e; pd = fmaf(e, s3.x, pd);
    e = __expf(lv3.y - m); ps += e; pd = fmaf(e, s3.y, pd);
    e = __expf(lv3.z - m); ps += e; pd = fmaf(e, s3.z, pd);
    e = __expf(lv3.w - m); ps += e; pd = fmaf(e, s3.w, pd);
  }
#pragma unroll
  for (int off = 32; off; off >>= 1) {
    ps += __shfl_xor(ps, off);
    pd += __shfl_xor(pd, off);
  }
  if (lane == 0) part[h] = pd / ps;
  __syncthreads();
  if (threadIdx.x == 0)
    vm[q] = (part[0] + part[1] + part[2] + part[3]) * (1.0f / 1024.0f);
}

extern "C" void kernel_launch(void* const* d_in, const int* in_sizes, int n_in,
                              void* d_out, int out_size, void* d_ws, size_t ws_size,
                              hipStream_t stream) {
  const float* q     = (const float*)d_in[0];
  const float* k     = (const float*)d_in[1];
  const float* v     = (const float*)d_in[2];
  const float* bias  = (const float*)d_in[3];
  const int*   mask  = (const int*)d_in[4];
  const float* Wq    = (const float*)d_in[5];
  const float* bq    = (const float*)d_in[6];
  const float* Wk    = (const float*)d_in[7];
  const float* bk    = (const float*)d_in[8];
  const float* Wbias = (const float*)d_in[9];
  const float* bbias = (const float*)d_in[10];
  const float* Wqo   = (const float*)d_in[11];
  const float* bqo   = (const float*)d_in[12];
  const float* Wko   = (const float*)d_in[13];
  const float* bko   = (const float*)d_in[14];
  const float* g_q   = (const float*)d_in[15];
  const float* be_q  = (const float*)d_in[16];
  const float* g_k   = (const float*)d_in[17];
  const float* be_k  = (const float*)d_in[18];
  const float* Wbo   = (const float*)d_in[19];
  const float* bbo   = (const float*)d_in[20];

  float* out = (float*)d_out;
  float* ws  = (float*)d_ws;
  float* projq = ws;                 // 1024x256
  float* projk = ws + 262144;        // 1024x256
  float* qo    = ws + 524288;        // 1024x256
  float* ko    = ws + 786432;        // 1024x256
  float* diffs = ws + 1048576;       // 4 x 1024 x 1024 (reused in-place as logits)
  float* svec  = ws + 5242880;       // 1024

  float* q_out    = out;             // 1024x256
  float* k_out    = out + 262144;    // 1024x256
  float* vmean    = out + 524288;    // 1024
  float* bias_out = out + 525312;    // 1024x1024x40

  svec_kernel<<<1024, 64, 0, stream>>>(v, svec);
  gemm1024<<<dim3(4, 16), 256, 0, stream>>>(q, Wq, bq, projq, 0);
  gemm1024<<<dim3(4, 16), 256, 0, stream>>>(k, Wk, bk, projk, 0);
  gemm1024<<<dim3(4, 16), 256, 0, stream>>>(projq, Wqo, bqo, qo, 1);
  gemm1024<<<dim3(4, 16), 256, 0, stream>>>(projk, Wko, bko, ko, 1);
  ln_epilogue<<<1024, 256, 0, stream>>>(q, qo, g_q, be_q, q_out);
  ln_epilogue<<<1024, 256, 0, stream>>>(k, ko, g_k, be_k, k_out);
  bias_mfma<<<1024, 256, 0, stream>>>(bias, Wbias, bbias, Wbo, bbo, diffs, bias_out);
  scores_kernel<<<dim3(16, 16, 4), 256, 0, stream>>>(projq, projk, mask, diffs);
  softmax_dot<<<1024, 256, 0, stream>>>(diffs, svec, vmean);
}

// Round 6
// 256.669 us; speedup vs baseline: 2.1437x; 2.1437x over previous
//
#include <hip/hip_runtime.h>
#include <hip/hip_bf16.h>
#include <math.h>

#define NEGV -9e15f

typedef short bf16x8 __attribute__((ext_vector_type(8)));
typedef float f32x4 __attribute__((ext_vector_type(4)));

__device__ __forceinline__ unsigned short f2bf(float x) {
  unsigned u = __float_as_uint(x);
  u += 0x7fffu + ((u >> 16) & 1u);
  return (unsigned short)(u >> 16);
}

__device__ __forceinline__ unsigned pk2(float a, float b) {
  __hip_bfloat162 h = __float22bfloat162_rn(make_float2(a, b));
  unsigned u;
  __builtin_memcpy(&u, &h, 4);
  return u;
}

// branchless mish: x * n/(n+2), n = u(u+2), u = e^min(x,30)
__device__ __forceinline__ float mishf(float x) {
  float u = __expf(fminf(x, 30.0f));
  float n = u * (u + 2.0f);
  return x * __fdividef(n, n + 2.0f);
}

// ---------------- s[k] = sum_vd v[k][vd] ----------------
__global__ void svec_kernel(const float* __restrict__ v, float* __restrict__ s) {
  int r = blockIdx.x;
  int lane = threadIdx.x;  // 64
  float4 a = *reinterpret_cast<const float4*>(v + (size_t)r * 256 + lane * 4);
  float x = a.x + a.y + a.z + a.w;
  for (int off = 32; off; off >>= 1) x += __shfl_down(x, off);
  if (lane == 0) s[r] = x;
}

// ---------------- C[1024x256] = A[1024x256] @ W[256x256] + bvec ----------------
__global__ __launch_bounds__(256) void gemm1024(
    const float* __restrict__ A, const float* __restrict__ W,
    const float* __restrict__ bvec, float* __restrict__ C, int perm) {
  __shared__ float sAT[16][68];
  __shared__ float sW[16][68];
  int tid = threadIdx.x;
  int c0 = blockIdx.x * 64, r0 = blockIdx.y * 64;
  int ty = tid >> 4, tx = tid & 15;
  float acc[4][4] = {};
  for (int k0 = 0; k0 < 256; k0 += 16) {
    {
      int r = tid >> 2, jq = tid & 3;
      float4 a4 = *reinterpret_cast<const float4*>(A + (size_t)(r0 + r) * 256 + k0 + jq * 4);
      sAT[jq * 4 + 0][r] = a4.x;
      sAT[jq * 4 + 1][r] = a4.y;
      sAT[jq * 4 + 2][r] = a4.z;
      sAT[jq * 4 + 3][r] = a4.w;
    }
    {
      int kk = tid >> 4, cq = tid & 15;
      int gk = k0 + kk;
      int row = perm ? ((gk & 63) * 4 + (gk >> 6)) : gk;
      float4 w4 = *reinterpret_cast<const float4*>(W + (size_t)row * 256 + c0 + cq * 4);
      *reinterpret_cast<float4*>(&sW[kk][cq * 4]) = w4;
    }
    __syncthreads();
#pragma unroll
    for (int kk = 0; kk < 16; ++kk) {
      float4 av = *reinterpret_cast<const float4*>(&sAT[kk][ty * 4]);
      float4 bv = *reinterpret_cast<const float4*>(&sW[kk][tx * 4]);
      float a[4] = {av.x, av.y, av.z, av.w};
      float b[4] = {bv.x, bv.y, bv.z, bv.w};
#pragma unroll
      for (int i = 0; i < 4; ++i)
#pragma unroll
        for (int j = 0; j < 4; ++j) acc[i][j] = fmaf(a[i], b[j], acc[i][j]);
    }
    __syncthreads();
  }
#pragma unroll
  for (int i = 0; i < 4; ++i) {
    int rr = r0 + ty * 4 + i, cc = c0 + tx * 4;
    float4 o;
    o.x = acc[i][0] + bvec[cc + 0];
    o.y = acc[i][1] + bvec[cc + 1];
    o.z = acc[i][2] + bvec[cc + 2];
    o.w = acc[i][3] + bvec[cc + 3];
    *reinterpret_cast<float4*>(C + (size_t)rr * 256 + cc) = o;
  }
}

// ---------------- out = LN(x0 + mish(y)) * g + be ----------------
__global__ __launch_bounds__(256) void ln_epilogue(
    const float* __restrict__ x0, const float* __restrict__ y,
    const float* __restrict__ g, const float* __restrict__ be,
    float* __restrict__ out) {
  __shared__ float r1[5], r2[5];
  int r = blockIdx.x, t = threadIdx.x;
  int wid = t >> 6, lane = t & 63;
  float x = x0[(size_t)r * 256 + t] + mishf(y[(size_t)r * 256 + t]);
  float a = x, b = x * x;
  for (int off = 32; off; off >>= 1) {
    a += __shfl_down(a, off);
    b += __shfl_down(b, off);
  }
  if (lane == 0) { r1[wid] = a; r2[wid] = b; }
  __syncthreads();
  if (t == 0) {
    r1[4] = r1[0] + r1[1] + r1[2] + r1[3];
    r2[4] = r2[0] + r2[1] + r2[2] + r2[3];
  }
  __syncthreads();
  float m = r1[4] * (1.0f / 256.0f);
  float var = r2[4] * (1.0f / 256.0f) - m * m;
  out[(size_t)r * 256 + t] = (x - m) * rsqrtf(var + 1e-5f) * g[t] + be[t];
}

// ---------------- fused bias path, MFMA bf16, single P buffer ----------------
#define PSTR 168  // bf16 elems per P row (160 + 8 pad) -> 336 B stride, 16B-aligned
#define BTILES 16

__device__ __forceinline__ void pack_store(unsigned short* p, f32x4 v) {
  uint2 w;
  w.x = pk2(v[0], v[1]);
  w.y = pk2(v[2], v[3]);
  *reinterpret_cast<uint2*>(p) = w;
}

// GEMM2 for tile with rows PO..PO+15 from per-wave P buffer SPR; Wo frags in regs
#define G2_STEP(SPR, PO) do {                                                          \
    bf16x8 pf0 = *reinterpret_cast<const bf16x8*>((SPR) + r * PSTR + 0 + g * 8);       \
    bf16x8 pf1 = *reinterpret_cast<const bf16x8*>((SPR) + r * PSTR + 32 + g * 8);      \
    bf16x8 pf2 = *reinterpret_cast<const bf16x8*>((SPR) + r * PSTR + 64 + g * 8);      \
    bf16x8 pf3 = *reinterpret_cast<const bf16x8*>((SPR) + r * PSTR + 96 + g * 8);      \
    bf16x8 pf4 = *reinterpret_cast<const bf16x8*>((SPR) + r * PSTR + 128 + g * 8);     \
    f32x4 o0 = {boreg0, boreg0, boreg0, boreg0};                                       \
    f32x4 o1 = {boreg1, boreg1, boreg1, boreg1};                                       \
    f32x4 o2 = {boreg2, boreg2, boreg2, boreg2};                                       \
    o0 = __builtin_amdgcn_mfma_f32_16x16x32_bf16(pf0, wof[0][0], o0, 0, 0, 0);         \
    o1 = __builtin_amdgcn_mfma_f32_16x16x32_bf16(pf0, wof[1][0], o1, 0, 0, 0);         \
    o2 = __builtin_amdgcn_mfma_f32_16x16x32_bf16(pf0, wof[2][0], o2, 0, 0, 0);         \
    o0 = __builtin_amdgcn_mfma_f32_16x16x32_bf16(pf1, wof[0][1], o0, 0, 0, 0);         \
    o1 = __builtin_amdgcn_mfma_f32_16x16x32_bf16(pf1, wof[1][1], o1, 0, 0, 0);         \
    o2 = __builtin_amdgcn_mfma_f32_16x16x32_bf16(pf1, wof[2][1], o2, 0, 0, 0);         \
    o0 = __builtin_amdgcn_mfma_f32_16x16x32_bf16(pf2, wof[0][2], o0, 0, 0, 0);         \
    o1 = __builtin_amdgcn_mfma_f32_16x16x32_bf16(pf2, wof[1][2], o1, 0, 0, 0);         \
    o2 = __builtin_amdgcn_mfma_f32_16x16x32_bf16(pf2, wof[2][2], o2, 0, 0, 0);         \
    o0 = __builtin_amdgcn_mfma_f32_16x16x32_bf16(pf3, wof[0][3], o0, 0, 0, 0);         \
    o1 = __builtin_amdgcn_mfma_f32_16x16x32_bf16(pf3, wof[1][3], o1, 0, 0, 0);         \
    o2 = __builtin_amdgcn_mfma_f32_16x16x32_bf16(pf3, wof[2][3], o2, 0, 0, 0);         \
    o0 = __builtin_amdgcn_mfma_f32_16x16x32_bf16(pf4, wof[0][4], o0, 0, 0, 0);         \
    o1 = __builtin_amdgcn_mfma_f32_16x16x32_bf16(pf4, wof[1][4], o1, 0, 0, 0);         \
    o2 = __builtin_amdgcn_mfma_f32_16x16x32_bf16(pf4, wof[2][4], o2, 0, 0, 0);         \
    float* bp = bout + (size_t)((PO) + g * 4) * 40;                                    \
    _Pragma("unroll")                                                                  \
    for (int reg = 0; reg < 4; ++reg) {                                                \
      bp[reg * 40 + r] = mishf(o0[reg]);                                               \
      bp[reg * 40 + 16 + r] = mishf(o1[reg]);                                          \
      if (r < 8) bp[reg * 40 + 32 + r] = mishf(o2[reg]);                               \
    }                                                                                  \
  } while (0)

// Per tile: build xf, prefetch t+1, G2(t-1) reads sP, G1(t) MFMAs+pack-writes sP, norms.
// Single buffer is safe: all G2 ds_reads precede G1 ds_writes; the 20 G1 MFMAs cover
// the WAR waitcnt.
#define TILE_STEP(SP, T, DOG2, DOPREF) do {                                            \
    const size_t p0 = row0 + (size_t)(T) * 16;                                         \
    bf16x8 xf0, xf1;                                                                   \
    {                                                                                  \
      uint4 t0 = {pk2(xA.x, xA.y), pk2(xA.z, xA.w), pk2(xB.x, xB.y), pk2(xB.z, xB.w)}; \
      unsigned d0 = (g == 1) ? 0x00003f80u : pk2(xC.x, xC.y);                          \
      uint4 t1 = {d0, pk2(xC.z, xC.w), pk2(xD.x, xD.y), pk2(xD.z, xD.w)};              \
      __builtin_memcpy(&xf0, &t0, 16);                                                 \
      __builtin_memcpy(&xf1, &t1, 16);                                                 \
    }                                                                                  \
    if (DOPREF) {                                                                      \
      const float* xr2 = bias + (p0 + 16 + r) * 40;                                    \
      xA = *reinterpret_cast<const float4*>(xr2 + g * 8);                              \
      xB = *reinterpret_cast<const float4*>(xr2 + g * 8 + 4);                          \
      xC = *reinterpret_cast<const float4*>(xr2 + 32);                                 \
      xD = *reinterpret_cast<const float4*>(xr2 + 36);                                 \
    }                                                                                  \
    if (DOG2) { G2_STEP(SP, p0 - 16); }                                                \
    float hv0, hv1, hv2, hv3;                                                          \
    {                                                                                  \
      f32x4 z = {0.0f, 0.0f, 0.0f, 0.0f};                                              \
      f32x4 q0 = z, q1 = z, q2 = z, q3 = z, q4 = z;                                    \
      q0 = __builtin_amdgcn_mfma_f32_16x16x32_bf16(wf[0][0], xf0, q0, 0, 0, 0);        \
      q1 = __builtin_amdgcn_mfma_f32_16x16x32_bf16(wf[1][0], xf0, q1, 0, 0, 0);        \
      q2 = __builtin_amdgcn_mfma_f32_16x16x32_bf16(wf[2][0], xf0, q2, 0, 0, 0);        \
      q3 = __builtin_amdgcn_mfma_f32_16x16x32_bf16(wf[3][0], xf0, q3, 0, 0, 0);        \
      q4 = __builtin_amdgcn_mfma_f32_16x16x32_bf16(wf[4][0], xf0, q4, 0, 0, 0);        \
      q0 = __builtin_amdgcn_mfma_f32_16x16x32_bf16(wf[0][1], xf1, q0, 0, 0, 0);        \
      q1 = __builtin_amdgcn_mfma_f32_16x16x32_bf16(wf[1][1], xf1, q1, 0, 0, 0);        \
      q2 = __builtin_amdgcn_mfma_f32_16x16x32_bf16(wf[2][1], xf1, q2, 0, 0, 0);        \
      q3 = __builtin_amdgcn_mfma_f32_16x16x32_bf16(wf[3][1], xf1, q3, 0, 0, 0);        \
      q4 = __builtin_amdgcn_mfma_f32_16x16x32_bf16(wf[4][1], xf1, q4, 0, 0, 0);        \
      float cs0 = q0[0]*q0[0] + q0[1]*q0[1] + q0[2]*q0[2] + q0[3]*q0[3];               \
      float cs1 = q1[0]*q1[0] + q1[1]*q1[1] + q1[2]*q1[2] + q1[3]*q1[3];               \
      float cs2 = q2[0]*q2[0] + q2[1]*q2[1] + q2[2]*q2[2] + q2[3]*q2[3];               \
      float cs3 = q3[0]*q3[0] + q3[1]*q3[1] + q3[2]*q3[2] + q3[3]*q3[3];               \
      float cs4 = q4[0]*q4[0] + q4[1]*q4[1] + q4[2]*q4[2] + q4[3]*q4[3];               \
      pack_store((SP) + r * PSTR + 0 * 16 + g * 4, q0);                                \
      pack_store((SP) + r * PSTR + 1 * 16 + g * 4, q1);                                \
      pack_store((SP) + r * PSTR + 2 * 16 + g * 4, q2);                                \
      pack_store((SP) + r * PSTR + 3 * 16 + g * 4, q3);                                \
      pack_store((SP) + r * PSTR + 4 * 16 + g * 4, q4);                                \
      hv0 = cs0 + cs1 + ((g < 2) ? cs2 : 0.0f);                                        \
      hv1 = ((g < 2) ? 0.0f : cs2) + cs3 + cs4;                                        \
    }                                                                                  \
    {                                                                                  \
      f32x4 z = {0.0f, 0.0f, 0.0f, 0.0f};                                              \
      f32x4 q0 = z, q1 = z, q2 = z, q3 = z, q4 = z;                                    \
      q0 = __builtin_amdgcn_mfma_f32_16x16x32_bf16(wf[5][0], xf0, q0, 0, 0, 0);        \
      q1 = __builtin_amdgcn_mfma_f32_16x16x32_bf16(wf[6][0], xf0, q1, 0, 0, 0);        \
      q2 = __builtin_amdgcn_mfma_f32_16x16x32_bf16(wf[7][0], xf0, q2, 0, 0, 0);        \
      q3 = __builtin_amdgcn_mfma_f32_16x16x32_bf16(wf[8][0], xf0, q3, 0, 0, 0);        \
      q4 = __builtin_amdgcn_mfma_f32_16x16x32_bf16(wf[9][0], xf0, q4, 0, 0, 0);        \
      q0 = __builtin_amdgcn_mfma_f32_16x16x32_bf16(wf[5][1], xf1, q0, 0, 0, 0);        \
      q1 = __builtin_amdgcn_mfma_f32_16x16x32_bf16(wf[6][1], xf1, q1, 0, 0, 0);        \
      q2 = __builtin_amdgcn_mfma_f32_16x16x32_bf16(wf[7][1], xf1, q2, 0, 0, 0);        \
      q3 = __builtin_amdgcn_mfma_f32_16x16x32_bf16(wf[8][1], xf1, q3, 0, 0, 0);        \
      q4 = __builtin_amdgcn_mfma_f32_16x16x32_bf16(wf[9][1], xf1, q4, 0, 0, 0);        \
      float cs5 = q0[0]*q0[0] + q0[1]*q0[1] + q0[2]*q0[2] + q0[3]*q0[3];               \
      float cs6 = q1[0]*q1[0] + q1[1]*q1[1] + q1[2]*q1[2] + q1[3]*q1[3];               \
      float cs7 = q2[0]*q2[0] + q2[1]*q2[1] + q2[2]*q2[2] + q2[3]*q2[3];               \
      float cs8 = q3[0]*q3[0] + q3[1]*q3[1] + q3[2]*q3[2] + q3[3]*q3[3];               \
      float cs9 = q4[0]*q4[0] + q4[1]*q4[1] + q4[2]*q4[2] + q4[3]*q4[3];               \
      pack_store((SP) + r * PSTR + 5 * 16 + g * 4, q0);                                \
      pack_store((SP) + r * PSTR + 6 * 16 + g * 4, q1);                                \
      pack_store((SP) + r * PSTR + 7 * 16 + g * 4, q2);                                \
      pack_store((SP) + r * PSTR + 8 * 16 + g * 4, q3);                                \
      pack_store((SP) + r * PSTR + 9 * 16 + g * 4, q4);                                \
      hv2 = cs5 + cs6 + ((g < 2) ? cs7 : 0.0f);                                        \
      hv3 = ((g < 2) ? 0.0f : cs7) + cs8 + cs9;                                        \
    }                                                                                  \
    hv0 += __shfl_xor(hv0, 16); hv0 += __shfl_xor(hv0, 32);                            \
    hv1 += __shfl_xor(hv1, 16); hv1 += __shfl_xor(hv1, 32);                            \
    hv2 += __shfl_xor(hv2, 16); hv2 += __shfl_xor(hv2, 32);                            \
    hv3 += __shfl_xor(hv3, 16); hv3 += __shfl_xor(hv3, 32);                            \
    float ss = (g == 0) ? hv0 : (g == 1) ? hv1 : (g == 2) ? hv2 : hv3;                 \
    diffs[(size_t)g * (1024 * 1024) + p0 + r] = sqrtf(ss);                             \
  } while (0)

__global__ __launch_bounds__(256, 2) void bias_mfma(
    const float* __restrict__ bias, const float* __restrict__ Wb,
    const float* __restrict__ bb, const float* __restrict__ Wo,
    const float* __restrict__ bo, float* __restrict__ diffs,
    float* __restrict__ bout) {
  __shared__ unsigned short sP[4][16 * PSTR];  // per-wave P buffer (single)
  int tid = threadIdx.x;
  int wv = tid >> 6, lane = tid & 63;
  int r = lane & 15, g = lane >> 4;

  // Wb^T fragments (A-operand): wf[n0][ks]; k=40 slot carries bb (bias fold)
  bf16x8 wf[10][2];
#pragma unroll
  for (int n0 = 0; n0 < 10; ++n0)
#pragma unroll
    for (int ks = 0; ks < 2; ++ks)
#pragma unroll
      for (int jj = 0; jj < 8; ++jj) {
        int k = ks * 32 + g * 8 + jj;
        int c = n0 * 16 + r;
        float w = (k < 40) ? Wb[k * 160 + c] : ((k == 40) ? bb[c] : 0.0f);
        wf[n0][ks][jj] = (short)f2bf(w);
      }
  // Wo^T fragments (B-operand for GEMM2): wof[n][ks]
  bf16x8 wof[3][5];
#pragma unroll
  for (int n = 0; n < 3; ++n)
#pragma unroll
    for (int ks = 0; ks < 5; ++ks)
#pragma unroll
      for (int jj = 0; jj < 8; ++jj) {
        int k = ks * 32 + g * 8 + jj;
        int c = n * 16 + r;
        wof[n][ks][jj] = (c < 40) ? (short)f2bf(Wo[k * 40 + c]) : (short)0;
      }
  float boreg0 = bo[r];
  float boreg1 = bo[16 + r];
  float boreg2 = (r < 8) ? bo[32 + r] : 0.0f;

  unsigned short* pP = &sP[wv][0];
  size_t row0 = ((size_t)blockIdx.x * 4 + wv) * (BTILES * 16);

  // prefetch tile 0
  const float* xr = bias + (row0 + r) * 40;
  float4 xA = *reinterpret_cast<const float4*>(xr + g * 8);
  float4 xB = *reinterpret_cast<const float4*>(xr + g * 8 + 4);
  float4 xC = *reinterpret_cast<const float4*>(xr + 32);
  float4 xD = *reinterpret_cast<const float4*>(xr + 36);

  TILE_STEP(pP, 0, false, true);
#pragma unroll 1
  for (int tt = 1; tt < BTILES - 1; ++tt) {
    TILE_STEP(pP, tt, true, true);
  }
  TILE_STEP(pP, BTILES - 1, true, false);
  G2_STEP(pP, row0 + (size_t)(BTILES - 1) * 16);
}

// ---------------- logits[h][q][k] = qk/8 + diffs, masked (in-place over diffs) ----------------
__global__ __launch_bounds__(256) void scores_kernel(
    const float* __restrict__ pq, const float* __restrict__ pk,
    const int* __restrict__ mask, float* __restrict__ logits) {
  __shared__ float sQT[64][68];
  __shared__ float sKT[64][68];
  int tid = threadIdx.x;
  int k0 = blockIdx.x * 64, q0 = blockIdx.y * 64, h = blockIdx.z;
  for (int i = tid; i < 1024; i += 256) {
    int r = i >> 4, dq = i & 15;
    float4 a = *reinterpret_cast<const float4*>(pq + (size_t)(q0 + r) * 256 + h * 64 + dq * 4);
    sQT[dq * 4 + 0][r] = a.x;
    sQT[dq * 4 + 1][r] = a.y;
    sQT[dq * 4 + 2][r] = a.z;
    sQT[dq * 4 + 3][r] = a.w;
    float4 b = *reinterpret_cast<const float4*>(pk + (size_t)(k0 + r) * 256 + h * 64 + dq * 4);
    sKT[dq * 4 + 0][r] = b.x;
    sKT[dq * 4 + 1][r] = b.y;
    sKT[dq * 4 + 2][r] = b.z;
    sKT[dq * 4 + 3][r] = b.w;
  }
  __syncthreads();
  int ty = tid >> 4, tx = tid & 15;
  float acc[4][4] = {};
#pragma unroll 4
  for (int d = 0; d < 64; ++d) {
    float4 av = *reinterpret_cast<const float4*>(&sQT[d][ty * 4]);
    float4 bv = *reinterpret_cast<const float4*>(&sKT[d][tx * 4]);
    float a[4] = {av.x, av.y, av.z, av.w};
    float b[4] = {bv.x, bv.y, bv.z, bv.w};
#pragma unroll
    for (int i = 0; i < 4; ++i)
#pragma unroll
      for (int j = 0; j < 4; ++j) acc[i][j] = fmaf(a[i], b[j], acc[i][j]);
  }
#pragma unroll
  for (int i = 0; i < 4; ++i) {
    int qq = q0 + ty * 4 + i;
    size_t base = (size_t)h * 1048576 + (size_t)qq * 1024 + k0 + tx * 4;
    float4 dv = *reinterpret_cast<const float4*>(logits + base);
    int4 mv = *reinterpret_cast<const int4*>(mask + (size_t)qq * 1024 + k0 + tx * 4);
    float4 o;
    o.x = (mv.x == 0) ? NEGV : fmaf(acc[i][0], 0.125f, dv.x);
    o.y = (mv.y == 0) ? NEGV : fmaf(acc[i][1], 0.125f, dv.y);
    o.z = (mv.z == 0) ? NEGV : fmaf(acc[i][2], 0.125f, dv.z);
    o.w = (mv.w == 0) ? NEGV : fmaf(acc[i][3], 0.125f, dv.w);
    *reinterpret_cast<float4*>(logits + base) = o;
  }
}

// ---------------- wave per (q, head): softmax over k, dot with s ----------------
__global__ __launch_bounds__(256) void softmax_dot(
    const float* __restrict__ logits, const float* __restrict__ sv,
    float* __restrict__ vm) {
  __shared__ float part[4];
  int q = blockIdx.x;
  int h = threadIdx.x >> 6, lane = threadIdx.x & 63;
  const float* lp = logits + (size_t)h * 1048576 + (size_t)q * 1024;
  float4 lv0 = *reinterpret_cast<const float4*>(lp + lane * 4);
  float4 lv1 = *reinterpret_cast<const float4*>(lp + 256 + lane * 4);
  float4 lv2 = *reinterpret_cast<const float4*>(lp + 512 + lane * 4);
  float4 lv3 = *reinterpret_cast<const float4*>(lp + 768 + lane * 4);
  float4 s0 = *reinterpret_cast<const float4*>(sv + lane * 4);
  float4 s1 = *reinterpret_cast<const float4*>(sv + 256 + lane * 4);
  float4 s2 = *reinterpret_cast<const float4*>(sv + 512 + lane * 4);
  float4 s3 = *reinterpret_cast<const float4*>(sv + 768 + lane * 4);
  float m = fmaxf(fmaxf(fmaxf(lv0.x, lv0.y), fmaxf(lv0.z, lv0.w)),
                  fmaxf(fmaxf(lv1.x, lv1.y), fmaxf(lv1.z, lv1.w)));
  m = fmaxf(m, fmaxf(fmaxf(fmaxf(lv2.x, lv2.y), fmaxf(lv2.z, lv2.w)),
                     fmaxf(fmaxf(lv3.x, lv3.y), fmaxf(lv3.z, lv3.w))));
#pragma unroll
  for (int off = 32; off; off >>= 1) m = fmaxf(m, __shfl_xor(m, off));
  float ps = 0.0f, pd = 0.0f;
  {
    float e;
    e = __expf(lv0.x - m); ps += e; pd = fmaf(e, s0.x, pd);
    e = __expf(lv0.y - m); ps += e; pd = fmaf(e, s0.y, pd);
    e = __expf(lv0.z - m); ps += e; pd = fmaf(e, s0.z, pd);
    e = __expf(lv0.w - m); ps += e; pd = fmaf(e, s0.w, pd);
    e = __expf(lv1.x - m); ps += e; pd = fmaf(e, s1.x, pd);
    e = __expf(lv1.y - m); ps += e; pd = fmaf(e, s1.y, pd);
    e = __expf(lv1.z - m); ps += e; pd = fmaf(e, s1.z, pd);
    e = __expf(lv1.w - m); ps += e; pd = fmaf(e, s1.w, pd);
    e = __expf(lv2.x - m); ps += e; pd = fmaf(e, s2.x, pd);
    e = __expf(lv2.y - m); ps += e; pd = fmaf(e, s2.y, pd);
    e = __expf(lv2.z - m); ps += e; pd = fmaf(e, s2.z, pd);
    e = __expf(lv2.w - m); ps += e; pd = fmaf(e, s2.w, pd);
    e = __expf(lv3.x - m); ps += e; pd = fmaf(e, s3.x, pd);
    e = __expf(lv3.y - m); ps += e; pd = fmaf(e, s3.y, pd);
    e = __expf(lv3.z - m); ps += e; pd = fmaf(e, s3.z, pd);
    e = __expf(lv3.w - m); ps += e; pd = fmaf(e, s3.w, pd);
  }
#pragma unroll
  for (int off = 32; off; off >>= 1) {
    ps += __shfl_xor(ps, off);
    pd += __shfl_xor(pd, off);
  }
  if (lane == 0) part[h] = pd / ps;
  __syncthreads();
  if (threadIdx.x == 0)
    vm[q] = (part[0] + part[1] + part[2] + part[3]) * (1.0f / 1024.0f);
}

extern "C" void kernel_launch(void* const* d_in, const int* in_sizes, int n_in,
                              void* d_out, int out_size, void* d_ws, size_t ws_size,
                              hipStream_t stream) {
  const float* q     = (const float*)d_in[0];
  const float* k     = (const float*)d_in[1];
  const float* v     = (const float*)d_in[2];
  const float* bias  = (const float*)d_in[3];
  const int*   mask  = (const int*)d_in[4];
  const float* Wq    = (const float*)d_in[5];
  const float* bq    = (const float*)d_in[6];
  const float* Wk    = (const float*)d_in[7];
  const float* bk    = (const float*)d_in[8];
  const float* Wbias = (const float*)d_in[9];
  const float* bbias = (const float*)d_in[10];
  const float* Wqo   = (const float*)d_in[11];
  const float* bqo   = (const float*)d_in[12];
  const float* Wko   = (const float*)d_in[13];
  const float* bko   = (const float*)d_in[14];
  const float* g_q   = (const float*)d_in[15];
  const float* be_q  = (const float*)d_in[16];
  const float* g_k   = (const float*)d_in[17];
  const float* be_k  = (const float*)d_in[18];
  const float* Wbo   = (const float*)d_in[19];
  const float* bbo   = (const float*)d_in[20];

  float* out = (float*)d_out;
  float* ws  = (float*)d_ws;
  float* projq = ws;                 // 1024x256
  float* projk = ws + 262144;        // 1024x256
  float* qo    = ws + 524288;        // 1024x256
  float* ko    = ws + 786432;        // 1024x256
  float* diffs = ws + 1048576;       // 4 x 1024 x 1024 (reused in-place as logits)
  float* svec  = ws + 5242880;       // 1024

  float* q_out    = out;             // 1024x256
  float* k_out    = out + 262144;    // 1024x256
  float* vmean    = out + 524288;    // 1024
  float* bias_out = out + 525312;    // 1024x1024x40

  svec_kernel<<<1024, 64, 0, stream>>>(v, svec);
  gemm1024<<<dim3(4, 16), 256, 0, stream>>>(q, Wq, bq, projq, 0);
  gemm1024<<<dim3(4, 16), 256, 0, stream>>>(k, Wk, bk, projk, 0);
  gemm1024<<<dim3(4, 16), 256, 0, stream>>>(projq, Wqo, bqo, qo, 1);
  gemm1024<<<dim3(4, 16), 256, 0, stream>>>(projk, Wko, bko, ko, 1);
  ln_epilogue<<<1024, 256, 0, stream>>>(q, qo, g_q, be_q, q_out);
  ln_epilogue<<<1024, 256, 0, stream>>>(k, ko, g_k, be_k, k_out);
  bias_mfma<<<1024, 256, 0, stream>>>(bias, Wbias, bbias, Wbo, bbo, diffs, bias_out);
  scores_kernel<<<dim3(16, 16, 4), 256, 0, stream>>>(projq, projk, mask, diffs);
  softmax_dot<<<1024, 256, 0, stream>>>(diffs, svec, vmean);
}

// Round 7
// 253.233 us; speedup vs baseline: 2.1728x; 1.0136x over previous
//
#include <hip/hip_runtime.h>
#include <hip/hip_bf16.h>
#include <math.h>

#define NEGV -9e15f

typedef short bf16x8 __attribute__((ext_vector_type(8)));
typedef float f32x4 __attribute__((ext_vector_type(4)));

__device__ __forceinline__ unsigned short f2bf(float x) {
  unsigned u = __float_as_uint(x);
  u += 0x7fffu + ((u >> 16) & 1u);
  return (unsigned short)(u >> 16);
}

__device__ __forceinline__ unsigned pk2(float a, float b) {
  __hip_bfloat162 h = __float22bfloat162_rn(make_float2(a, b));
  unsigned u;
  __builtin_memcpy(&u, &h, 4);
  return u;
}

// branchless mish: x * n/(n+2), n = u(u+2), u = e^min(x,30)
__device__ __forceinline__ float mishf(float x) {
  float u = __expf(fminf(x, 30.0f));
  float n = u * (u + 2.0f);
  return x * __fdividef(n, n + 2.0f);
}

// ---------------- s[k] = sum_vd v[k][vd] ----------------
__global__ void svec_kernel(const float* __restrict__ v, float* __restrict__ s) {
  int r = blockIdx.x;
  int lane = threadIdx.x;  // 64
  float4 a = *reinterpret_cast<const float4*>(v + (size_t)r * 256 + lane * 4);
  float x = a.x + a.y + a.z + a.w;
  for (int off = 32; off; off >>= 1) x += __shfl_down(x, off);
  if (lane == 0) s[r] = x;
}

// ---------------- C[1024x256] = A[1024x256] @ W[256x256] + bvec ----------------
__global__ __launch_bounds__(256) void gemm1024(
    const float* __restrict__ A, const float* __restrict__ W,
    const float* __restrict__ bvec, float* __restrict__ C, int perm) {
  __shared__ float sAT[16][68];
  __shared__ float sW[16][68];
  int tid = threadIdx.x;
  int c0 = blockIdx.x * 64, r0 = blockIdx.y * 64;
  int ty = tid >> 4, tx = tid & 15;
  float acc[4][4] = {};
  for (int k0 = 0; k0 < 256; k0 += 16) {
    {
      int r = tid >> 2, jq = tid & 3;
      float4 a4 = *reinterpret_cast<const float4*>(A + (size_t)(r0 + r) * 256 + k0 + jq * 4);
      sAT[jq * 4 + 0][r] = a4.x;
      sAT[jq * 4 + 1][r] = a4.y;
      sAT[jq * 4 + 2][r] = a4.z;
      sAT[jq * 4 + 3][r] = a4.w;
    }
    {
      int kk = tid >> 4, cq = tid & 15;
      int gk = k0 + kk;
      int row = perm ? ((gk & 63) * 4 + (gk >> 6)) : gk;
      float4 w4 = *reinterpret_cast<const float4*>(W + (size_t)row * 256 + c0 + cq * 4);
      *reinterpret_cast<float4*>(&sW[kk][cq * 4]) = w4;
    }
    __syncthreads();
#pragma unroll
    for (int kk = 0; kk < 16; ++kk) {
      float4 av = *reinterpret_cast<const float4*>(&sAT[kk][ty * 4]);
      float4 bv = *reinterpret_cast<const float4*>(&sW[kk][tx * 4]);
      float a[4] = {av.x, av.y, av.z, av.w};
      float b[4] = {bv.x, bv.y, bv.z, bv.w};
#pragma unroll
      for (int i = 0; i < 4; ++i)
#pragma unroll
        for (int j = 0; j < 4; ++j) acc[i][j] = fmaf(a[i], b[j], acc[i][j]);
    }
    __syncthreads();
  }
#pragma unroll
  for (int i = 0; i < 4; ++i) {
    int rr = r0 + ty * 4 + i, cc = c0 + tx * 4;
    float4 o;
    o.x = acc[i][0] + bvec[cc + 0];
    o.y = acc[i][1] + bvec[cc + 1];
    o.z = acc[i][2] + bvec[cc + 2];
    o.w = acc[i][3] + bvec[cc + 3];
    *reinterpret_cast<float4*>(C + (size_t)rr * 256 + cc) = o;
  }
}

// ---------------- out = LN(x0 + mish(y)) * g + be ----------------
__global__ __launch_bounds__(256) void ln_epilogue(
    const float* __restrict__ x0, const float* __restrict__ y,
    const float* __restrict__ g, const float* __restrict__ be,
    float* __restrict__ out) {
  __shared__ float r1[5], r2[5];
  int r = blockIdx.x, t = threadIdx.x;
  int wid = t >> 6, lane = t & 63;
  float x = x0[(size_t)r * 256 + t] + mishf(y[(size_t)r * 256 + t]);
  float a = x, b = x * x;
  for (int off = 32; off; off >>= 1) {
    a += __shfl_down(a, off);
    b += __shfl_down(b, off);
  }
  if (lane == 0) { r1[wid] = a; r2[wid] = b; }
  __syncthreads();
  if (t == 0) {
    r1[4] = r1[0] + r1[1] + r1[2] + r1[3];
    r2[4] = r2[0] + r2[1] + r2[2] + r2[3];
  }
  __syncthreads();
  float m = r1[4] * (1.0f / 256.0f);
  float var = r2[4] * (1.0f / 256.0f) - m * m;
  out[(size_t)r * 256 + t] = (x - m) * rsqrtf(var + 1e-5f) * g[t] + be[t];
}

// ---------------- fused bias path, MFMA bf16, single P buffer ----------------
#define PSTR 168  // bf16 elems per P row (160 + 8 pad) -> 336 B stride, 16B-aligned
#define BTILES 16

__device__ __forceinline__ void pack_store(unsigned short* p, f32x4 v) {
  uint2 w;
  w.x = pk2(v[0], v[1]);
  w.y = pk2(v[2], v[3]);
  *reinterpret_cast<uint2*>(p) = w;
}

// GEMM2 (swapped operands): o_n = mfma(wof[n], pf) -> lane (r,g) holds
// out[row PO+r][cols 16n+4g..+3] => coalesced float4 stores.
#define G2_STEP(SPR, PO) do {                                                          \
    bf16x8 pf0 = *reinterpret_cast<const bf16x8*>((SPR) + r * PSTR + 0 + g * 8);       \
    bf16x8 pf1 = *reinterpret_cast<const bf16x8*>((SPR) + r * PSTR + 32 + g * 8);      \
    bf16x8 pf2 = *reinterpret_cast<const bf16x8*>((SPR) + r * PSTR + 64 + g * 8);      \
    bf16x8 pf3 = *reinterpret_cast<const bf16x8*>((SPR) + r * PSTR + 96 + g * 8);     \
    bf16x8 pf4 = *reinterpret_cast<const bf16x8*>((SPR) + r * PSTR + 128 + g * 8);     \
    f32x4 o0 = bo40, o1 = bo41, o2 = bo42;                                             \
    o0 = __builtin_amdgcn_mfma_f32_16x16x32_bf16(wof[0][0], pf0, o0, 0, 0, 0);         \
    o1 = __builtin_amdgcn_mfma_f32_16x16x32_bf16(wof[1][0], pf0, o1, 0, 0, 0);         \
    o2 = __builtin_amdgcn_mfma_f32_16x16x32_bf16(wof[2][0], pf0, o2, 0, 0, 0);         \
    o0 = __builtin_amdgcn_mfma_f32_16x16x32_bf16(wof[0][1], pf1, o0, 0, 0, 0);         \
    o1 = __builtin_amdgcn_mfma_f32_16x16x32_bf16(wof[1][1], pf1, o1, 0, 0, 0);         \
    o2 = __builtin_amdgcn_mfma_f32_16x16x32_bf16(wof[2][1], pf1, o2, 0, 0, 0);         \
    o0 = __builtin_amdgcn_mfma_f32_16x16x32_bf16(wof[0][2], pf2, o0, 0, 0, 0);         \
    o1 = __builtin_amdgcn_mfma_f32_16x16x32_bf16(wof[1][2], pf2, o1, 0, 0, 0);         \
    o2 = __builtin_amdgcn_mfma_f32_16x16x32_bf16(wof[2][2], pf2, o2, 0, 0, 0);         \
    o0 = __builtin_amdgcn_mfma_f32_16x16x32_bf16(wof[0][3], pf3, o0, 0, 0, 0);         \
    o1 = __builtin_amdgcn_mfma_f32_16x16x32_bf16(wof[1][3], pf3, o1, 0, 0, 0);         \
    o2 = __builtin_amdgcn_mfma_f32_16x16x32_bf16(wof[2][3], pf3, o2, 0, 0, 0);         \
    o0 = __builtin_amdgcn_mfma_f32_16x16x32_bf16(wof[0][4], pf4, o0, 0, 0, 0);         \
    o1 = __builtin_amdgcn_mfma_f32_16x16x32_bf16(wof[1][4], pf4, o1, 0, 0, 0);         \
    o2 = __builtin_amdgcn_mfma_f32_16x16x32_bf16(wof[2][4], pf4, o2, 0, 0, 0);         \
    float* bp = bout + (size_t)((PO) + r) * 40;                                        \
    float4 st;                                                                         \
    st.x = mishf(o0[0]); st.y = mishf(o0[1]);                                          \
    st.z = mishf(o0[2]); st.w = mishf(o0[3]);                                          \
    *reinterpret_cast<float4*>(bp + 4 * g) = st;                                       \
    st.x = mishf(o1[0]); st.y = mishf(o1[1]);                                          \
    st.z = mishf(o1[2]); st.w = mishf(o1[3]);                                          \
    *reinterpret_cast<float4*>(bp + 16 + 4 * g) = st;                                  \
    if (g < 2) {                                                                       \
      st.x = mishf(o2[0]); st.y = mishf(o2[1]);                                        \
      st.z = mishf(o2[2]); st.w = mishf(o2[3]);                                        \
      *reinterpret_cast<float4*>(bp + 32 + 4 * g) = st;                                \
    }                                                                                  \
  } while (0)

// Per tile: build xf, prefetch t+1, G2(t-1) reads sP, G1(t) MFMAs+pack-writes sP, norms.
// Single buffer is safe: all G2 ds_reads precede G1 ds_writes; the 20 G1 MFMAs cover
// the WAR waitcnt.
#define TILE_STEP(SP, T, DOG2, DOPREF) do {                                            \
    const size_t p0 = row0 + (size_t)(T) * 16;                                         \
    bf16x8 xf0, xf1;                                                                   \
    {                                                                                  \
      uint4 t0 = {pk2(xA.x, xA.y), pk2(xA.z, xA.w), pk2(xB.x, xB.y), pk2(xB.z, xB.w)}; \
      unsigned d0 = (g == 1) ? 0x00003f80u : pk2(xC.x, xC.y);                          \
      uint4 t1 = {d0, pk2(xC.z, xC.w), pk2(xD.x, xD.y), pk2(xD.z, xD.w)};              \
      __builtin_memcpy(&xf0, &t0, 16);                                                 \
      __builtin_memcpy(&xf1, &t1, 16);                                                 \
    }                                                                                  \
    if (DOPREF) {                                                                      \
      const float* xr2 = bias + (p0 + 16 + r) * 40;                                    \
      xA = *reinterpret_cast<const float4*>(xr2 + g * 8);                              \
      xB = *reinterpret_cast<const float4*>(xr2 + g * 8 + 4);                          \
      xC = *reinterpret_cast<const float4*>(xr2 + 32);                                 \
      xD = *reinterpret_cast<const float4*>(xr2 + 36);                                 \
    }                                                                                  \
    if (DOG2) { G2_STEP(SP, p0 - 16); }                                                \
    float hv0, hv1, hv2, hv3;                                                          \
    {                                                                                  \
      f32x4 z = {0.0f, 0.0f, 0.0f, 0.0f};                                              \
      f32x4 q0 = z, q1 = z, q2 = z, q3 = z, q4 = z;                                    \
      q0 = __builtin_amdgcn_mfma_f32_16x16x32_bf16(wf[0][0], xf0, q0, 0, 0, 0);        \
      q1 = __builtin_amdgcn_mfma_f32_16x16x32_bf16(wf[1][0], xf0, q1, 0, 0, 0);        \
      q2 = __builtin_amdgcn_mfma_f32_16x16x32_bf16(wf[2][0], xf0, q2, 0, 0, 0);        \
      q3 = __builtin_amdgcn_mfma_f32_16x16x32_bf16(wf[3][0], xf0, q3, 0, 0, 0);        \
      q4 = __builtin_amdgcn_mfma_f32_16x16x32_bf16(wf[4][0], xf0, q4, 0, 0, 0);        \
      q0 = __builtin_amdgcn_mfma_f32_16x16x32_bf16(wf[0][1], xf1, q0, 0, 0, 0);        \
      q1 = __builtin_amdgcn_mfma_f32_16x16x32_bf16(wf[1][1], xf1, q1, 0, 0, 0);        \
      q2 = __builtin_amdgcn_mfma_f32_16x16x32_bf16(wf[2][1], xf1, q2, 0, 0, 0);        \
      q3 = __builtin_amdgcn_mfma_f32_16x16x32_bf16(wf[3][1], xf1, q3, 0, 0, 0);        \
      q4 = __builtin_amdgcn_mfma_f32_16x16x32_bf16(wf[4][1], xf1, q4, 0, 0, 0);        \
      float cs0 = q0[0]*q0[0] + q0[1]*q0[1] + q0[2]*q0[2] + q0[3]*q0[3];               \
      float cs1 = q1[0]*q1[0] + q1[1]*q1[1] + q1[2]*q1[2] + q1[3]*q1[3];               \
      float cs2 = q2[0]*q2[0] + q2[1]*q2[1] + q2[2]*q2[2] + q2[3]*q2[3];               \
      float cs3 = q3[0]*q3[0] + q3[1]*q3[1] + q3[2]*q3[2] + q3[3]*q3[3];               \
      float cs4 = q4[0]*q4[0] + q4[1]*q4[1] + q4[2]*q4[2] + q4[3]*q4[3];               \
      pack_store((SP) + r * PSTR + 0 * 16 + g * 4, q0);                                \
      pack_store((SP) + r * PSTR + 1 * 16 + g * 4, q1);                                \
      pack_store((SP) + r * PSTR + 2 * 16 + g * 4, q2);                                \
      pack_store((SP) + r * PSTR + 3 * 16 + g * 4, q3);                                \
      pack_store((SP) + r * PSTR + 4 * 16 + g * 4, q4);                                \
      hv0 = cs0 + cs1 + ((g < 2) ? cs2 : 0.0f);                                        \
      hv1 = ((g < 2) ? 0.0f : cs2) + cs3 + cs4;                                        \
    }                                                                                  \
    {                                                                                  \
      f32x4 z = {0.0f, 0.0f, 0.0f, 0.0f};                                              \
      f32x4 q0 = z, q1 = z, q2 = z, q3 = z, q4 = z;                                    \
      q0 = __builtin_amdgcn_mfma_f32_16x16x32_bf16(wf[5][0], xf0, q0, 0, 0, 0);        \
      q1 = __builtin_amdgcn_mfma_f32_16x16x32_bf16(wf[6][0], xf0, q1, 0, 0, 0);        \
      q2 = __builtin_amdgcn_mfma_f32_16x16x32_bf16(wf[7][0], xf0, q2, 0, 0, 0);        \
      q3 = __builtin_amdgcn_mfma_f32_16x16x32_bf16(wf[8][0], xf0, q3, 0, 0, 0);        \
      q4 = __builtin_amdgcn_mfma_f32_16x16x32_bf16(wf[9][0], xf0, q4, 0, 0, 0);        \
      q0 = __builtin_amdgcn_mfma_f32_16x16x32_bf16(wf[5][1], xf1, q0, 0, 0, 0);        \
      q1 = __builtin_amdgcn_mfma_f32_16x16x32_bf16(wf[6][1], xf1, q1, 0, 0, 0);        \
      q2 = __builtin_amdgcn_mfma_f32_16x16x32_bf16(wf[7][1], xf1, q2, 0, 0, 0);        \
      q3 = __builtin_amdgcn_mfma_f32_16x16x32_bf16(wf[8][1], xf1, q3, 0, 0, 0);        \
      q4 = __builtin_amdgcn_mfma_f32_16x16x32_bf16(wf[9][1], xf1, q4, 0, 0, 0);        \
      float cs5 = q0[0]*q0[0] + q0[1]*q0[1] + q0[2]*q0[2] + q0[3]*q0[3];               \
      float cs6 = q1[0]*q1[0] + q1[1]*q1[1] + q1[2]*q1[2] + q1[3]*q1[3];               \
      float cs7 = q2[0]*q2[0] + q2[1]*q2[1] + q2[2]*q2[2] + q2[3]*q2[3];               \
      float cs8 = q3[0]*q3[0] + q3[1]*q3[1] + q3[2]*q3[2] + q3[3]*q3[3];               \
      float cs9 = q4[0]*q4[0] + q4[1]*q4[1] + q4[2]*q4[2] + q4[3]*q4[3];               \
      pack_store((SP) + r * PSTR + 5 * 16 + g * 4, q0);                                \
      pack_store((SP) + r * PSTR + 6 * 16 + g * 4, q1);                                \
      pack_store((SP) + r * PSTR + 7 * 16 + g * 4, q2);                                \
      pack_store((SP) + r * PSTR + 8 * 16 + g * 4, q3);                                \
      pack_store((SP) + r * PSTR + 9 * 16 + g * 4, q4);                                \
      hv2 = cs5 + cs6 + ((g < 2) ? cs7 : 0.0f);                                        \
      hv3 = ((g < 2) ? 0.0f : cs7) + cs8 + cs9;                                        \
    }                                                                                  \
    hv0 += __shfl_xor(hv0, 16); hv0 += __shfl_xor(hv0, 32);                            \
    hv1 += __shfl_xor(hv1, 16); hv1 += __shfl_xor(hv1, 32);                            \
    hv2 += __shfl_xor(hv2, 16); hv2 += __shfl_xor(hv2, 32);                            \
    hv3 += __shfl_xor(hv3, 16); hv3 += __shfl_xor(hv3, 32);                            \
    float ss = (g == 0) ? hv0 : (g == 1) ? hv1 : (g == 2) ? hv2 : hv3;                 \
    diffs[(size_t)g * (1024 * 1024) + p0 + r] = sqrtf(ss);                             \
  } while (0)

__global__ __launch_bounds__(256, 2) void bias_mfma(
    const float* __restrict__ bias, const float* __restrict__ Wb,
    const float* __restrict__ bb, const float* __restrict__ Wo,
    const float* __restrict__ bo, float* __restrict__ diffs,
    float* __restrict__ bout) {
  __shared__ unsigned short sP[4][16 * PSTR];  // per-wave P buffer (single)
  int tid = threadIdx.x;
  int wv = tid >> 6, lane = tid & 63;
  int r = lane & 15, g = lane >> 4;

  // Wb^T fragments (A-operand): wf[n0][ks]; k=40 slot carries bb (bias fold)
  bf16x8 wf[10][2];
#pragma unroll
  for (int n0 = 0; n0 < 10; ++n0)
#pragma unroll
    for (int ks = 0; ks < 2; ++ks)
#pragma unroll
      for (int jj = 0; jj < 8; ++jj) {
        int k = ks * 32 + g * 8 + jj;
        int c = n0 * 16 + r;
        float w = (k < 40) ? Wb[k * 160 + c] : ((k == 40) ? bb[c] : 0.0f);
        wf[n0][ks][jj] = (short)f2bf(w);
      }
  // Wo^T fragments (A-operand for swapped GEMM2): wof[n][ks]
  bf16x8 wof[3][5];
#pragma unroll
  for (int n = 0; n < 3; ++n)
#pragma unroll
    for (int ks = 0; ks < 5; ++ks)
#pragma unroll
      for (int jj = 0; jj < 8; ++jj) {
        int k = ks * 32 + g * 8 + jj;
        int c = n * 16 + r;
        wof[n][ks][jj] = (c < 40) ? (short)f2bf(Wo[k * 40 + c]) : (short)0;
      }
  // bo as per-lane float4: cols 16n + 4g .. +3
  f32x4 bo40, bo41, bo42;
  {
    float4 t0 = *reinterpret_cast<const float4*>(bo + 4 * g);
    float4 t1 = *reinterpret_cast<const float4*>(bo + 16 + 4 * g);
    bo40[0] = t0.x; bo40[1] = t0.y; bo40[2] = t0.z; bo40[3] = t0.w;
    bo41[0] = t1.x; bo41[1] = t1.y; bo41[2] = t1.z; bo41[3] = t1.w;
    if (g < 2) {
      float4 t2 = *reinterpret_cast<const float4*>(bo + 32 + 4 * g);
      bo42[0] = t2.x; bo42[1] = t2.y; bo42[2] = t2.z; bo42[3] = t2.w;
    } else {
      bo42[0] = 0.0f; bo42[1] = 0.0f; bo42[2] = 0.0f; bo42[3] = 0.0f;
    }
  }

  unsigned short* pP = &sP[wv][0];
  size_t row0 = ((size_t)blockIdx.x * 4 + wv) * (BTILES * 16);

  // prefetch tile 0
  const float* xr = bias + (row0 + r) * 40;
  float4 xA = *reinterpret_cast<const float4*>(xr + g * 8);
  float4 xB = *reinterpret_cast<const float4*>(xr + g * 8 + 4);
  float4 xC = *reinterpret_cast<const float4*>(xr + 32);
  float4 xD = *reinterpret_cast<const float4*>(xr + 36);

  TILE_STEP(pP, 0, false, true);
#pragma unroll 1
  for (int tt = 1; tt < BTILES - 1; ++tt) {
    TILE_STEP(pP, tt, true, true);
  }
  TILE_STEP(pP, BTILES - 1, true, false);
  G2_STEP(pP, row0 + (size_t)(BTILES - 1) * 16);
}

// ---------------- logits[h][q][k] = qk/8 + diffs, masked (in-place over diffs) ----------------
__global__ __launch_bounds__(256) void scores_kernel(
    const float* __restrict__ pq, const float* __restrict__ pk,
    const int* __restrict__ mask, float* __restrict__ logits) {
  __shared__ float sQT[64][68];
  __shared__ float sKT[64][68];
  int tid = threadIdx.x;
  int k0 = blockIdx.x * 64, q0 = blockIdx.y * 64, h = blockIdx.z;
  for (int i = tid; i < 1024; i += 256) {
    int r = i >> 4, dq = i & 15;
    float4 a = *reinterpret_cast<const float4*>(pq + (size_t)(q0 + r) * 256 + h * 64 + dq * 4);
    sQT[dq * 4 + 0][r] = a.x;
    sQT[dq * 4 + 1][r] = a.y;
    sQT[dq * 4 + 2][r] = a.z;
    sQT[dq * 4 + 3][r] = a.w;
    float4 b = *reinterpret_cast<const float4*>(pk + (size_t)(k0 + r) * 256 + h * 64 + dq * 4);
    sKT[dq * 4 + 0][r] = b.x;
    sKT[dq * 4 + 1][r] = b.y;
    sKT[dq * 4 + 2][r] = b.z;
    sKT[dq * 4 + 3][r] = b.w;
  }
  __syncthreads();
  int ty = tid >> 4, tx = tid & 15;
  float acc[4][4] = {};
#pragma unroll 4
  for (int d = 0; d < 64; ++d) {
    float4 av = *reinterpret_cast<const float4*>(&sQT[d][ty * 4]);
    float4 bv = *reinterpret_cast<const float4*>(&sKT[d][tx * 4]);
    float a[4] = {av.x, av.y, av.z, av.w};
    float b[4] = {bv.x, bv.y, bv.z, bv.w};
#pragma unroll
    for (int i = 0; i < 4; ++i)
#pragma unroll
      for (int j = 0; j < 4; ++j) acc[i][j] = fmaf(a[i], b[j], acc[i][j]);
  }
#pragma unroll
  for (int i = 0; i < 4; ++i) {
    int qq = q0 + ty * 4 + i;
    size_t base = (size_t)h * 1048576 + (size_t)qq * 1024 + k0 + tx * 4;
    float4 dv = *reinterpret_cast<const float4*>(logits + base);
    int4 mv = *reinterpret_cast<const int4*>(mask + (size_t)qq * 1024 + k0 + tx * 4);
    float4 o;
    o.x = (mv.x == 0) ? NEGV : fmaf(acc[i][0], 0.125f, dv.x);
    o.y = (mv.y == 0) ? NEGV : fmaf(acc[i][1], 0.125f, dv.y);
    o.z = (mv.z == 0) ? NEGV : fmaf(acc[i][2], 0.125f, dv.z);
    o.w = (mv.w == 0) ? NEGV : fmaf(acc[i][3], 0.125f, dv.w);
    *reinterpret_cast<float4*>(logits + base) = o;
  }
}

// ---------------- wave per (q, head): softmax over k, dot with s ----------------
__global__ __launch_bounds__(256) void softmax_dot(
    const float* __restrict__ logits, const float* __restrict__ sv,
    float* __restrict__ vm) {
  __shared__ float part[4];
  int q = blockIdx.x;
  int h = threadIdx.x >> 6, lane = threadIdx.x & 63;
  const float* lp = logits + (size_t)h * 1048576 + (size_t)q * 1024;
  float4 lv0 = *reinterpret_cast<const float4*>(lp + lane * 4);
  float4 lv1 = *reinterpret_cast<const float4*>(lp + 256 + lane * 4);
  float4 lv2 = *reinterpret_cast<const float4*>(lp + 512 + lane * 4);
  float4 lv3 = *reinterpret_cast<const float4*>(lp + 768 + lane * 4);
  float4 s0 = *reinterpret_cast<const float4*>(sv + lane * 4);
  float4 s1 = *reinterpret_cast<const float4*>(sv + 256 + lane * 4);
  float4 s2 = *reinterpret_cast<const float4*>(sv + 512 + lane * 4);
  float4 s3 = *reinterpret_cast<const float4*>(sv + 768 + lane * 4);
  float m = fmaxf(fmaxf(fmaxf(lv0.x, lv0.y), fmaxf(lv0.z, lv0.w)),
                  fmaxf(fmaxf(lv1.x, lv1.y), fmaxf(lv1.z, lv1.w)));
  m = fmaxf(m, fmaxf(fmaxf(fmaxf(lv2.x, lv2.y), fmaxf(lv2.z, lv2.w)),
                     fmaxf(fmaxf(lv3.x, lv3.y), fmaxf(lv3.z, lv3.w))));
#pragma unroll
  for (int off = 32; off; off >>= 1) m = fmaxf(m, __shfl_xor(m, off));
  float ps = 0.0f, pd = 0.0f;
  {
    float e;
    e = __expf(lv0.x - m); ps += e; pd = fmaf(e, s0.x, pd);
    e = __expf(lv0.y - m); ps += e; pd = fmaf(e, s0.y, pd);
    e = __expf(lv0.z - m); ps += e; pd = fmaf(e, s0.z, pd);
    e = __expf(lv0.w - m); ps += e; pd = fmaf(e, s0.w, pd);
    e = __expf(lv1.x - m); ps += e; pd = fmaf(e, s1.x, pd);
    e = __expf(lv1.y - m); ps += e; pd = fmaf(e, s1.y, pd);
    e = __expf(lv1.z - m); ps += e; pd = fmaf(e, s1.z, pd);
    e = __expf(lv1.w - m); ps += e; pd = fmaf(e, s1.w, pd);
    e = __expf(lv2.x - m); ps += e; pd = fmaf(e, s2.x, pd);
    e = __expf(lv2.y - m); ps += e; pd = fmaf(e, s2.y, pd);
    e = __expf(lv2.z - m); ps += e; pd = fmaf(e, s2.z, pd);
    e = __expf(lv2.w - m); ps += e; pd = fmaf(e, s2.w, pd);
    e = __expf(lv3.x - m); ps += e; pd = fmaf(e, s3.x, pd);
    e = __expf(lv3.y - m); ps += e; pd = fmaf(e, s3.y, pd);
    e = __expf(lv3.z - m); ps += e; pd = fmaf(e, s3.z, pd);
    e = __expf(lv3.w - m); ps += e; pd = fmaf(e, s3.w, pd);
  }
#pragma unroll
  for (int off = 32; off; off >>= 1) {
    ps += __shfl_xor(ps, off);
    pd += __shfl_xor(pd, off);
  }
  if (lane == 0) part[h] = pd / ps;
  __syncthreads();
  if (threadIdx.x == 0)
    vm[q] = (part[0] + part[1] + part[2] + part[3]) * (1.0f / 1024.0f);
}

extern "C" void kernel_launch(void* const* d_in, const int* in_sizes, int n_in,
                              void* d_out, int out_size, void* d_ws, size_t ws_size,
                              hipStream_t stream) {
  const float* q     = (const float*)d_in[0];
  const float* k     = (const float*)d_in[1];
  const float* v     = (const float*)d_in[2];
  const float* bias  = (const float*)d_in[3];
  const int*   mask  = (const int*)d_in[4];
  const float* Wq    = (const float*)d_in[5];
  const float* bq    = (const float*)d_in[6];
  const float* Wk    = (const float*)d_in[7];
  const float* bk    = (const float*)d_in[8];
  const float* Wbias = (const float*)d_in[9];
  const float* bbias = (const float*)d_in[10];
  const float* Wqo   = (const float*)d_in[11];
  const float* bqo   = (const float*)d_in[12];
  const float* Wko   = (const float*)d_in[13];
  const float* bko   = (const float*)d_in[14];
  const float* g_q   = (const float*)d_in[15];
  const float* be_q  = (const float*)d_in[16];
  const float* g_k   = (const float*)d_in[17];
  const float* be_k  = (const float*)d_in[18];
  const float* Wbo   = (const float*)d_in[19];
  const float* bbo   = (const float*)d_in[20];

  float* out = (float*)d_out;
  float* ws  = (float*)d_ws;
  float* projq = ws;                 // 1024x256
  float* projk = ws + 262144;        // 1024x256
  float* qo    = ws + 524288;        // 1024x256
  float* ko    = ws + 786432;        // 1024x256
  float* diffs = ws + 1048576;       // 4 x 1024 x 1024 (reused in-place as logits)
  float* svec  = ws + 5242880;       // 1024

  float* q_out    = out;             // 1024x256
  float* k_out    = out + 262144;    // 1024x256
  float* vmean    = out + 524288;    // 1024
  float* bias_out = out + 525312;    // 1024x1024x40

  svec_kernel<<<1024, 64, 0, stream>>>(v, svec);
  gemm1024<<<dim3(4, 16), 256, 0, stream>>>(q, Wq, bq, projq, 0);
  gemm1024<<<dim3(4, 16), 256, 0, stream>>>(k, Wk, bk, projk, 0);
  gemm1024<<<dim3(4, 16), 256, 0, stream>>>(projq, Wqo, bqo, qo, 1);
  gemm1024<<<dim3(4, 16), 256, 0, stream>>>(projk, Wko, bko, ko, 1);
  ln_epilogue<<<1024, 256, 0, stream>>>(q, qo, g_q, be_q, q_out);
  ln_epilogue<<<1024, 256, 0, stream>>>(k, ko, g_k, be_k, k_out);
  bias_mfma<<<1024, 256, 0, stream>>>(bias, Wbias, bbias, Wbo, bbo, diffs, bias_out);
  scores_kernel<<<dim3(16, 16, 4), 256, 0, stream>>>(projq, projk, mask, diffs);
  softmax_dot<<<1024, 256, 0, stream>>>(diffs, svec, vmean);
}